// Round 3
// baseline (349.360 us; speedup 1.0000x reference)
//
#include <hip/hip_runtime.h>

#define D 64
#define CAP 64            // per-node bucket capacity (Poisson(16): P(deg>64) ~ 1e-17)
#define NPB 32            // nodes per coarse bucket (bucket = c >> 5)
#define SCAN_THREADS 1024

// ---- K1: coarse-bucket histogram (fire-and-forget atomics) ----------------
__global__ void hist_kernel(const int* __restrict__ col, int* __restrict__ hist, int E) {
    int e = blockIdx.x * blockDim.x + threadIdx.x;
    if (e < E) atomicAdd(&hist[col[e] >> 5], 1);
}

// ---- K2: exclusive scan of hist -> start[], cursor[] (single block) -------
__global__ void __launch_bounds__(SCAN_THREADS) scan_kernel(
    const int* __restrict__ hist, int* __restrict__ start,
    int* __restrict__ cursor, int NB)
{
    __shared__ int part[SCAN_THREADS];
    int t = threadIdx.x;
    int i0 = 2 * t, i1 = 2 * t + 1;
    int h0 = (i0 < NB) ? hist[i0] : 0;
    int h1 = (i1 < NB) ? hist[i1] : 0;
    int p = h0 + h1;
    part[t] = p;
    __syncthreads();
    // Hillis-Steele inclusive scan over 1024 partials
    for (int off = 1; off < SCAN_THREADS; off <<= 1) {
        int v = part[t];
        int add = (t >= off) ? part[t - off] : 0;
        __syncthreads();
        part[t] = v + add;
        __syncthreads();
    }
    int incl = part[t];
    int base = incl - p;          // exclusive prefix for this thread's chunk
    if (i0 < NB) { start[i0] = base;      cursor[i0] = base; }
    if (i1 < NB) { start[i1] = base + h0; cursor[i1] = base + h0; }
    if (t == SCAN_THREADS - 1) start[NB] = incl;   // total == E
}

// ---- K3: partition edges into coarse buckets (sequential write streams) ---
__global__ void scatter_kernel(const int* __restrict__ row, const int* __restrict__ col,
                               int* __restrict__ cursor, unsigned int* __restrict__ packed, int E)
{
    int e = blockIdx.x * blockDim.x + threadIdx.x;
    if (e >= E) return;
    int r = row[e], c = col[e];
    int pos = atomicAdd(&cursor[c >> 5], 1);
    packed[pos] = ((unsigned int)c << 16) | (unsigned int)r;   // both < 65536
}

// ---- K4: bin within bucket via LDS; coalesced srcs write; fuse cnt+dinv ---
__global__ void __launch_bounds__(256) bin_kernel(
    const unsigned int* __restrict__ packed, const int* __restrict__ start,
    unsigned short* __restrict__ srcs, int* __restrict__ cnt, float* __restrict__ dinv,
    int* __restrict__ ovf_cnt, int2* __restrict__ ovf, int n, int NB)
{
    __shared__ unsigned short lbuf[NPB * CAP];
    __shared__ int lcnt[NPB];
    int b = blockIdx.x;
    if (b >= NB) return;
    int tid = threadIdx.x;
    if (tid < NPB) lcnt[tid] = 0;
    __syncthreads();

    int s0 = start[b], s1 = start[b + 1];
    int lo = b * NPB;
    for (int i = s0 + tid; i < s1; i += 256) {
        unsigned int v = packed[i];
        int c = (int)(v >> 16);
        int r = (int)(v & 0xffffu);
        int ln = c - lo;
        int slot = atomicAdd(&lcnt[ln], 1);
        if (slot < CAP) {
            lbuf[ln * CAP + slot] = (unsigned short)r;
        } else {
            int oi = atomicAdd(ovf_cnt, 1);
            ovf[oi] = make_int2(r, c);
        }
    }
    __syncthreads();

    // coalesced write-out: srcs[(lo + idx/CAP)*CAP + idx%CAP] == srcs[lo*CAP + idx]
    for (int idx = tid; idx < NPB * CAP; idx += 256) {
        int node = lo + (idx >> 6);
        if (node < n) srcs[(size_t)lo * CAP + idx] = lbuf[idx];
    }
    if (tid < NPB) {
        int node = lo + tid;
        if (node < n) {
            int dg = lcnt[tid];
            cnt[node] = dg;
            dinv[node] = rsqrtf((float)dg + 1.0f);
        }
    }
}

// ---- K5: h = x @ W^T ------------------------------------------------------
__global__ void __launch_bounds__(256) gemm_kernel(
    const float* __restrict__ x, const float* __restrict__ W,
    float* __restrict__ h, int n)
{
    __shared__ float Ws[D * 65];
    __shared__ float xs[4][D];

    int tid = threadIdx.x;
    #pragma unroll
    for (int k = 0; k < 16; ++k) {
        int idx = tid + k * 256;
        int o = idx >> 6, i = idx & 63;
        Ws[o * 65 + i] = W[idx];
    }

    int ln = tid >> 6;
    int o  = tid & 63;
    int node = blockIdx.x * 4 + ln;
    if (node < n) {
        xs[ln][o] = x[node * D + o];
    }
    __syncthreads();

    if (node >= n) return;

    float sum = 0.0f;
    #pragma unroll
    for (int i = 0; i < D; ++i) {
        sum += xs[ln][i] * Ws[o * 65 + i];
    }
    h[node * D + o] = sum;
}

// ---- K6: per-target gather; bias + (conditional) PReLU fused --------------
__global__ void __launch_bounds__(256) gather_kernel(
    const int* __restrict__ cnt, const unsigned short* __restrict__ srcs,
    const float* __restrict__ dinv, const float* __restrict__ h,
    const float* __restrict__ b, const float* __restrict__ prelu_a,
    const int* __restrict__ ovf_cnt, float* __restrict__ out, int n)
{
    int wave = (blockIdx.x * blockDim.x + threadIdx.x) >> 6;
    int lane = threadIdx.x & 63;
    if (wave >= n) return;
    int c = wave;

    int deg = cnt[c];
    int m = deg < CAP ? deg : CAP;
    float dc = dinv[c];

    int   s  = 0;
    float wl = 0.0f;
    if (lane < m) {
        s  = (int)srcs[(size_t)c * CAP + lane];
        wl = dinv[s] * dc;
    }

    float acc = h[(size_t)c * D + lane] * dc * dc + b[lane];

    for (int k = 0; k < m; ++k) {
        int   sk = __shfl(s,  k);
        float wk = __shfl(wl, k);
        acc += h[(size_t)sk * D + lane] * wk;
    }

    if (*ovf_cnt == 0) {   // common path: overflow empty -> activate now
        float al = prelu_a[0];
        acc = acc >= 0.0f ? acc : al * acc;
    }
    out[(size_t)c * D + lane] = acc;
}

// ---- K7: overflow fallback (normally zero iterations) ---------------------
__global__ void overflow_kernel(const int* __restrict__ ovf_cnt, const int2* __restrict__ ovf,
                                const float* __restrict__ dinv, const float* __restrict__ h,
                                float* __restrict__ out)
{
    int nov = *ovf_cnt;
    if (nov == 0) return;
    int wave = (blockIdx.x * blockDim.x + threadIdx.x) >> 6;
    int lane = threadIdx.x & 63;
    int nwaves = (gridDim.x * blockDim.x) >> 6;
    for (int i = wave; i < nov; i += nwaves) {
        int r = ovf[i].x, c = ovf[i].y;
        atomicAdd(&out[(size_t)c * D + lane], h[(size_t)r * D + lane] * dinv[r] * dinv[c]);
    }
}

// ---- K8: PReLU fix-up, only if overflow path ran --------------------------
__global__ void prelu_fix_kernel(float* __restrict__ out, const float* __restrict__ a,
                                 const int* __restrict__ ovf_cnt, int total)
{
    if (*ovf_cnt == 0) return;
    int i = blockIdx.x * blockDim.x + threadIdx.x;
    if (i < total) {
        float v = out[i];
        float alpha = a[0];
        out[i] = v >= 0.0f ? v : alpha * v;
    }
}

extern "C" void kernel_launch(void* const* d_in, const int* in_sizes, int n_in,
                              void* d_out, int out_size, void* d_ws, size_t ws_size,
                              hipStream_t stream) {
    const float* x       = (const float*)d_in[0];
    const int*   eidx    = (const int*)d_in[1];   // [2, E] flat
    const float* W       = (const float*)d_in[2];
    const float* b       = (const float*)d_in[3];
    const float* prelu_a = (const float*)d_in[4];

    const int E = in_sizes[1] / 2;
    const int n = in_sizes[0] / D;                // 50000
    const int NB = (n + NPB - 1) / NPB;           // 1563 coarse buckets
    const int* row = eidx;
    const int* col = eidx + E;

    float* out = (float*)d_out;

    // Workspace layout (4B units unless noted):
    //   hist    int[NB]
    //   ovf_cnt int[1]          (adjacent to hist -> one memset)
    //   pad     int[1]
    //   cursor  int[NB]
    //   start   int[NB+1]
    //   pad to even
    //   packed  uint[E]
    //   ovf     int2[E]         (8B aligned)
    //   cnt     int[n]
    //   dinv    float[n]
    //   srcs    ushort[n*CAP]
    //   h       float[n*D]
    int* hist    = (int*)d_ws;
    int* ovf_cnt = hist + NB;
    int* cursor  = hist + NB + 2;
    int* start   = cursor + NB;
    int* p       = start + NB + 1;
    if ((((uintptr_t)p) & 7) != 0) p += 1;        // 8B align
    unsigned int* packed = (unsigned int*)p;
    int2*  ovf   = (int2*)(packed + E);
    int*   cnt   = (int*)(ovf + E);
    float* dinv  = (float*)(cnt + n);
    unsigned short* srcs = (unsigned short*)(dinv + n);
    float* h     = (float*)(srcs + (size_t)n * CAP);

    // zero hist + ovf_cnt
    hipMemsetAsync(hist, 0, (size_t)(NB + 1) * sizeof(int), stream);

    hist_kernel<<<(E + 255) / 256, 256, 0, stream>>>(col, hist, E);

    scan_kernel<<<1, SCAN_THREADS, 0, stream>>>(hist, start, cursor, NB);

    scatter_kernel<<<(E + 255) / 256, 256, 0, stream>>>(row, col, cursor, packed, E);

    bin_kernel<<<NB, 256, 0, stream>>>(packed, start, srcs, cnt, dinv, ovf_cnt, ovf, n, NB);

    gemm_kernel<<<(n + 3) / 4, 256, 0, stream>>>(x, W, h, n);

    gather_kernel<<<(n * 64 + 255) / 256, 256, 0, stream>>>(
        cnt, srcs, dinv, h, b, prelu_a, ovf_cnt, out, n);

    overflow_kernel<<<64, 256, 0, stream>>>(ovf_cnt, ovf, dinv, h, out);

    prelu_fix_kernel<<<(n * D + 255) / 256, 256, 0, stream>>>(out, prelu_a, ovf_cnt, n * D);
}

// Round 4
// 147.363 us; speedup vs baseline: 2.3708x; 2.3708x over previous
//
#include <hip/hip_runtime.h>

#define D 64
#define CAP 64            // per-node list capacity (Poisson(16): P(deg>64) ~ 1e-19)
#define GROUPS 8          // node-range groups, mapped to XCDs via bid % 8

// ---- K1: XCD-local bucket fill --------------------------------------------
// Blocks with bid%8==g handle only targets in node range g. Each XCD's L2
// then holds only a ~0.8MB srcs window -> random 2B writes merge in L2.
// cnt[] doubles as the degree histogram.
__global__ void __launch_bounds__(256) fill_kernel(
    const int* __restrict__ row, const int* __restrict__ col,
    int* __restrict__ cnt, unsigned short* __restrict__ srcs,
    int* __restrict__ ovf_cnt, int2* __restrict__ ovf, int E, int n)
{
    int g   = blockIdx.x & (GROUPS - 1);          // group == XCD (round-robin)
    int bg  = blockIdx.x >> 3;                    // block index within group
    int bpg = gridDim.x >> 3;                     // blocks per group
    int npg = (n + GROUPS - 1) / GROUPS;          // nodes per group
    int lo  = g * npg;
    int hi  = lo + npg < n ? lo + npg : n;

    int stride = bpg * 256;
    for (int e = bg * 256 + threadIdx.x; e < E; e += stride) {
        int c = col[e];
        if (c < lo || c >= hi) continue;          // not this XCD's range
        int r = row[e];
        int slot = atomicAdd(&cnt[c], 1);
        if (slot < CAP) {
            srcs[(size_t)c * CAP + slot] = (unsigned short)r;
        } else {
            int oi = atomicAdd(ovf_cnt, 1);       // capacity E, never overflows
            ovf[oi] = make_int2(r, c);
        }
    }
}

// ---- K2: dinv = rsqrt(deg + 1) (self-loop folded in) ----------------------
__global__ void dinv_kernel(const int* __restrict__ cnt, float* __restrict__ dinv, int n) {
    int i = blockIdx.x * blockDim.x + threadIdx.x;
    if (i < n) {
        dinv[i] = rsqrtf((float)cnt[i] + 1.0f);
    }
}

// ---- K3: h = x @ W^T ------------------------------------------------------
// Block = 256 threads = 4 nodes x 64 output channels. W staged in LDS padded.
__global__ void __launch_bounds__(256) gemm_kernel(
    const float* __restrict__ x, const float* __restrict__ W,
    float* __restrict__ h, int n)
{
    __shared__ float Ws[D * 65];   // padded stride 65 -> conflict-free
    __shared__ float xs[4][D];

    int tid = threadIdx.x;
    #pragma unroll
    for (int k = 0; k < 16; ++k) {
        int idx = tid + k * 256;
        int o = idx >> 6, i = idx & 63;
        Ws[o * 65 + i] = W[idx];
    }

    int ln = tid >> 6;
    int o  = tid & 63;
    int node = blockIdx.x * 4 + ln;
    if (node < n) {
        xs[ln][o] = x[node * D + o];
    }
    __syncthreads();

    if (node >= n) return;

    float sum = 0.0f;
    #pragma unroll
    for (int i = 0; i < D; ++i) {
        sum += xs[ln][i] * Ws[o * 65 + i];
    }
    h[node * D + o] = sum;
}

// ---- K4: per-target gather; bias + (conditional) PReLU fused --------------
// One wave per target node; lane = output channel. No output atomics.
__global__ void __launch_bounds__(256) gather_kernel(
    const int* __restrict__ cnt, const unsigned short* __restrict__ srcs,
    const float* __restrict__ dinv, const float* __restrict__ h,
    const float* __restrict__ b, const float* __restrict__ prelu_a,
    const int* __restrict__ ovf_cnt, float* __restrict__ out, int n)
{
    int wave = (blockIdx.x * blockDim.x + threadIdx.x) >> 6;
    int lane = threadIdx.x & 63;
    if (wave >= n) return;
    int c = wave;

    int deg = cnt[c];
    int m = deg < CAP ? deg : CAP;
    float dc = dinv[c];

    // lane j holds source j and its edge weight (one coalesced 128B read)
    int   s  = 0;
    float wl = 0.0f;
    if (lane < m) {
        s  = (int)srcs[(size_t)c * CAP + lane];
        wl = dinv[s] * dc;
    }

    // self-loop term + bias
    float acc = h[(size_t)c * D + lane] * dc * dc + b[lane];

    for (int k = 0; k < m; ++k) {
        int   sk = __shfl(s,  k);
        float wk = __shfl(wl, k);
        acc += h[(size_t)sk * D + lane] * wk;
    }

    if (*ovf_cnt == 0) {   // common path: overflow empty -> activate now
        float al = prelu_a[0];
        acc = acc >= 0.0f ? acc : al * acc;
    }
    out[(size_t)c * D + lane] = acc;
}

// ---- K5: overflow fallback (normally zero iterations) ---------------------
__global__ void overflow_kernel(const int* __restrict__ ovf_cnt, const int2* __restrict__ ovf,
                                const float* __restrict__ dinv, const float* __restrict__ h,
                                float* __restrict__ out)
{
    int nov = *ovf_cnt;
    if (nov == 0) return;
    int wave = (blockIdx.x * blockDim.x + threadIdx.x) >> 6;
    int lane = threadIdx.x & 63;
    int nwaves = (gridDim.x * blockDim.x) >> 6;
    for (int i = wave; i < nov; i += nwaves) {
        int r = ovf[i].x, c = ovf[i].y;
        atomicAdd(&out[(size_t)c * D + lane], h[(size_t)r * D + lane] * dinv[r] * dinv[c]);
    }
}

// ---- K6: PReLU fix-up, only if the overflow path ran ----------------------
__global__ void prelu_fix_kernel(float* __restrict__ out, const float* __restrict__ a,
                                 const int* __restrict__ ovf_cnt, int total)
{
    if (*ovf_cnt == 0) return;
    int i = blockIdx.x * blockDim.x + threadIdx.x;
    if (i < total) {
        float v = out[i];
        float alpha = a[0];
        out[i] = v >= 0.0f ? v : alpha * v;
    }
}

extern "C" void kernel_launch(void* const* d_in, const int* in_sizes, int n_in,
                              void* d_out, int out_size, void* d_ws, size_t ws_size,
                              hipStream_t stream) {
    const float* x       = (const float*)d_in[0];
    const int*   eidx    = (const int*)d_in[1];   // [2, E] flat
    const float* W       = (const float*)d_in[2];
    const float* b       = (const float*)d_in[3];
    const float* prelu_a = (const float*)d_in[4];

    const int E = in_sizes[1] / 2;
    const int n = in_sizes[0] / D;                // 50000
    const int* row = eidx;
    const int* col = eidx + E;

    float* out = (float*)d_out;

    // Workspace layout:
    //   cnt      int[n]
    //   ovf_cnt  int[1]
    //   pad      int[1]            (keeps ovf 8B aligned)
    //   ovf      int2[E]
    //   dinv     float[n]
    //   srcs     ushort[n*CAP]     (6.4 MB)
    //   h        float[n*D]        (12.8 MB)
    int*   cnt     = (int*)d_ws;
    int*   ovf_cnt = cnt + n;
    int2*  ovf     = (int2*)(cnt + n + 2);
    float* dinv    = (float*)(ovf + E);
    unsigned short* srcs = (unsigned short*)(dinv + n);
    float* h       = (float*)(srcs + (size_t)n * CAP);

    // zero cnt + ovf_cnt (adjacent)
    hipMemsetAsync(cnt, 0, (size_t)(n + 1) * sizeof(int), stream);

    // 512 blocks = 64 per XCD group
    fill_kernel<<<512, 256, 0, stream>>>(row, col, cnt, srcs, ovf_cnt, ovf, E, n);

    dinv_kernel<<<(n + 255) / 256, 256, 0, stream>>>(cnt, dinv, n);

    gemm_kernel<<<(n + 3) / 4, 256, 0, stream>>>(x, W, h, n);

    gather_kernel<<<(n * 64 + 255) / 256, 256, 0, stream>>>(
        cnt, srcs, dinv, h, b, prelu_a, ovf_cnt, out, n);

    overflow_kernel<<<64, 256, 0, stream>>>(ovf_cnt, ovf, dinv, h, out);

    prelu_fix_kernel<<<(n * D + 255) / 256, 256, 0, stream>>>(out, prelu_a, ovf_cnt, n * D);
}

// Round 5
// 104.361 us; speedup vs baseline: 3.3476x; 1.4120x over previous
//
#include <hip/hip_runtime.h>
#include <hip/hip_bf16.h>

#define D 64
#define CAP 64            // per-node list capacity (Poisson(16): P(deg>64) ~ 1e-19)
#define GROUPS 8          // node-range groups, mapped to XCDs via bid % 8

// ---- K1: XCD-local bucket fill, int4-vectorized edge reads ----------------
// Blocks with bid%8==g handle only targets in node range g (srcs window
// ~0.8MB -> L2-resident). row/col read unconditionally, coalesced, 16B/thread.
__global__ void __launch_bounds__(256) fill_kernel(
    const int* __restrict__ row, const int* __restrict__ col,
    const int4* __restrict__ row4, const int4* __restrict__ col4,
    int* __restrict__ cnt, unsigned short* __restrict__ srcs,
    int* __restrict__ ovf_cnt, int2* __restrict__ ovf, int E, int E4, int n)
{
    int g   = blockIdx.x & (GROUPS - 1);
    int bg  = blockIdx.x >> 3;
    int bpg = gridDim.x >> 3;
    int npg = (n + GROUPS - 1) / GROUPS;
    int lo  = g * npg;
    int hi  = lo + npg < n ? lo + npg : n;
    int stride = bpg * 256;

    for (int i = bg * 256 + threadIdx.x; i < E4; i += stride) {
        int4 cc = col4[i];
        int4 rr = row4[i];
        #pragma unroll
        for (int j = 0; j < 4; ++j) {
            int c = (j == 0) ? cc.x : (j == 1) ? cc.y : (j == 2) ? cc.z : cc.w;
            int r = (j == 0) ? rr.x : (j == 1) ? rr.y : (j == 2) ? rr.z : rr.w;
            if (c >= lo && c < hi) {
                int slot = atomicAdd(&cnt[c], 1);
                if (slot < CAP) {
                    srcs[(size_t)c * CAP + slot] = (unsigned short)r;
                } else {
                    int oi = atomicAdd(ovf_cnt, 1);
                    ovf[oi] = make_int2(r, c);
                }
            }
        }
    }
    // remainder edges (E % 4, or everything if int4 path disabled)
    for (int e = E4 * 4 + bg * 256 + threadIdx.x; e < E; e += stride) {
        int c = col[e];
        if (c >= lo && c < hi) {
            int r = row[e];
            int slot = atomicAdd(&cnt[c], 1);
            if (slot < CAP) {
                srcs[(size_t)c * CAP + slot] = (unsigned short)r;
            } else {
                int oi = atomicAdd(ovf_cnt, 1);
                ovf[oi] = make_int2(r, c);
            }
        }
    }
}

// ---- K2: h = x @ W^T, stored as bf16 ---------------------------------------
// Block = 256 threads = 4 nodes x 64 output channels. W staged in LDS padded.
__global__ void __launch_bounds__(256) gemm_kernel(
    const float* __restrict__ x, const float* __restrict__ W,
    __hip_bfloat16* __restrict__ h, int n)
{
    __shared__ float Ws[D * 65];   // padded stride 65 -> conflict-free
    __shared__ float xs[4][D];

    int tid = threadIdx.x;
    #pragma unroll
    for (int k = 0; k < 16; ++k) {
        int idx = tid + k * 256;
        int o = idx >> 6, i = idx & 63;
        Ws[o * 65 + i] = W[idx];
    }

    int ln = tid >> 6;
    int o  = tid & 63;
    int node = blockIdx.x * 4 + ln;
    if (node < n) {
        xs[ln][o] = x[node * D + o];
    }
    __syncthreads();

    if (node >= n) return;

    float sum = 0.0f;
    #pragma unroll
    for (int i = 0; i < D; ++i) {
        sum += xs[ln][i] * Ws[o * 65 + i];
    }
    h[(size_t)node * D + o] = __float2bfloat16(sum);
}

// ---- K3: per-target gather, 8-wide MLP; bias+PReLU+overflow fused ----------
// One wave per target node; lane = output channel. No output atomics.
__global__ void __launch_bounds__(256) gather_kernel(
    const int* __restrict__ cnt, const unsigned short* __restrict__ srcs,
    const __hip_bfloat16* __restrict__ h,
    const float* __restrict__ b, const float* __restrict__ prelu_a,
    const int* __restrict__ ovf_cnt, const int2* __restrict__ ovf,
    float* __restrict__ out, int n)
{
    int wave = (blockIdx.x * blockDim.x + threadIdx.x) >> 6;
    int lane = threadIdx.x & 63;
    if (wave >= n) return;
    int c = wave;

    int deg = cnt[c];
    int m = deg < CAP ? deg : CAP;
    float dc = rsqrtf((float)deg + 1.0f);

    // lane j holds source j and its edge weight (one coalesced 128B read)
    int   s  = 0;
    float wl = 0.0f;
    if (lane < m) {
        s  = (int)srcs[(size_t)c * CAP + lane];
        wl = rsqrtf((float)cnt[s] + 1.0f) * dc;
    }

    // self-loop term + bias
    float acc = __bfloat162float(h[(size_t)c * D + lane]) * dc * dc + b[lane];

    // 8-wide unrolled edge loop: batch shuffles, then 8 independent loads.
    // Lanes k+j >= m broadcast wl==0, s==0 -> contributes exactly 0.
    int m8 = (m + 7) & ~7;
    for (int k = 0; k < m8; k += 8) {
        int   ss[8];
        float ww[8];
        #pragma unroll
        for (int j = 0; j < 8; ++j) {
            ss[j] = __shfl(s,  k + j);
            ww[j] = __shfl(wl, k + j);
        }
        float vv[8];
        #pragma unroll
        for (int j = 0; j < 8; ++j) {
            vv[j] = __bfloat162float(h[(size_t)ss[j] * D + lane]);
        }
        #pragma unroll
        for (int j = 0; j < 8; ++j) {
            acc += vv[j] * ww[j];
        }
    }

    // overflow fallback (nov == 0 in practice: single scalar load)
    int nov = *ovf_cnt;
    for (int i = 0; i < nov; ++i) {
        int2 rc = ovf[i];
        if (rc.y == c) {
            acc += __bfloat162float(h[(size_t)rc.x * D + lane]) *
                   rsqrtf((float)cnt[rc.x] + 1.0f) * dc;
        }
    }

    float al = prelu_a[0];
    out[(size_t)c * D + lane] = acc >= 0.0f ? acc : al * acc;
}

extern "C" void kernel_launch(void* const* d_in, const int* in_sizes, int n_in,
                              void* d_out, int out_size, void* d_ws, size_t ws_size,
                              hipStream_t stream) {
    const float* x       = (const float*)d_in[0];
    const int*   eidx    = (const int*)d_in[1];   // [2, E] flat
    const float* W       = (const float*)d_in[2];
    const float* b       = (const float*)d_in[3];
    const float* prelu_a = (const float*)d_in[4];

    const int E = in_sizes[1] / 2;
    const int n = in_sizes[0] / D;                // 50000
    const int* row = eidx;
    const int* col = eidx + E;

    float* out = (float*)d_out;

    // int4 path only if both halves are 16B-aligned (E % 4 == 0 guarantees
    // col's offset alignment given a 16B-aligned base allocation)
    int E4 = 0;
    if ((E % 4) == 0 &&
        ((uintptr_t)row % 16) == 0 && ((uintptr_t)col % 16) == 0) {
        E4 = E / 4;
    }

    // Workspace layout:
    //   cnt      int[n]
    //   ovf_cnt  int[1]
    //   pad      int[1]            (keeps ovf 8B aligned)
    //   ovf      int2[E]
    //   h        bf16[n*D]         (6.4 MB)
    //   srcs     ushort[n*CAP]     (6.4 MB)
    int*   cnt     = (int*)d_ws;
    int*   ovf_cnt = cnt + n;
    int2*  ovf     = (int2*)(cnt + n + 2);
    __hip_bfloat16* h = (__hip_bfloat16*)(ovf + E);
    unsigned short* srcs = (unsigned short*)(h + (size_t)n * D);

    // zero cnt + ovf_cnt (adjacent)
    hipMemsetAsync(cnt, 0, (size_t)(n + 1) * sizeof(int), stream);

    // 2048 blocks = 256 per XCD group
    fill_kernel<<<2048, 256, 0, stream>>>(
        row, col, (const int4*)row, (const int4*)col,
        cnt, srcs, ovf_cnt, ovf, E, E4, n);

    gemm_kernel<<<(n + 3) / 4, 256, 0, stream>>>(x, W, h, n);

    gather_kernel<<<(n * 64 + 255) / 256, 256, 0, stream>>>(
        cnt, srcs, h, b, prelu_a, ovf_cnt, ovf, out, n);
}

// Round 6
// 100.228 us; speedup vs baseline: 3.4856x; 1.0412x over previous
//
#include <hip/hip_runtime.h>
#include <hip/hip_bf16.h>

#define D 64
#define CAP 64            // per-node list capacity (Poisson(16): P(deg>64) ~ 1e-19)
#define GROUPS 8          // node-range groups, mapped to XCDs via bid % 8
#define ZERO_BLOCKS 49    // 49*256 int4 = 50176 int4 >= ceil(50002/4)

// ---- K1: h = x @ W^T (bf16 out), fused cnt zeroing -------------------------
// Block = 256 threads = 4 nodes x 64 output channels. W staged in LDS padded.
// First ZERO_BLOCKS blocks additionally zero cnt[n] + ovf_cnt (int4 stores).
__global__ void __launch_bounds__(256) gemm_zero_kernel(
    const float* __restrict__ x, const float* __restrict__ W,
    __hip_bfloat16* __restrict__ h, int4* __restrict__ cnt4, int nzero4, int n)
{
    if (blockIdx.x < ZERO_BLOCKS) {
        int i = blockIdx.x * 256 + threadIdx.x;
        if (i < nzero4) cnt4[i] = make_int4(0, 0, 0, 0);
    }

    __shared__ float Ws[D * 65];   // padded stride 65 -> conflict-free
    __shared__ float xs[4][D];

    int tid = threadIdx.x;
    #pragma unroll
    for (int k = 0; k < 16; ++k) {
        int idx = tid + k * 256;
        int o = idx >> 6, i = idx & 63;
        Ws[o * 65 + i] = W[idx];
    }

    int ln = tid >> 6;
    int o  = tid & 63;
    int node = blockIdx.x * 4 + ln;
    if (node < n) {
        xs[ln][o] = x[node * D + o];
    }
    __syncthreads();

    if (node >= n) return;

    float sum = 0.0f;
    #pragma unroll
    for (int i = 0; i < D; ++i) {
        sum += xs[ln][i] * Ws[o * 65 + i];
    }
    h[(size_t)node * D + o] = __float2bfloat16(sum);
}

// ---- K2: XCD-local bucket fill, int4-vectorized edge reads ----------------
// Blocks with bid%8==g handle only targets in node range g (srcs window
// ~0.8MB -> L2-resident). row/col read unconditionally, coalesced, 16B/thread.
__global__ void __launch_bounds__(256) fill_kernel(
    const int* __restrict__ row, const int* __restrict__ col,
    const int4* __restrict__ row4, const int4* __restrict__ col4,
    int* __restrict__ cnt, unsigned short* __restrict__ srcs,
    int* __restrict__ ovf_cnt, int2* __restrict__ ovf, int E, int E4, int n)
{
    int g   = blockIdx.x & (GROUPS - 1);
    int bg  = blockIdx.x >> 3;
    int bpg = gridDim.x >> 3;
    int npg = (n + GROUPS - 1) / GROUPS;
    int lo  = g * npg;
    int hi  = lo + npg < n ? lo + npg : n;
    int stride = bpg * 256;

    for (int i = bg * 256 + threadIdx.x; i < E4; i += stride) {
        int4 cc = col4[i];
        int4 rr = row4[i];
        #pragma unroll
        for (int j = 0; j < 4; ++j) {
            int c = (j == 0) ? cc.x : (j == 1) ? cc.y : (j == 2) ? cc.z : cc.w;
            int r = (j == 0) ? rr.x : (j == 1) ? rr.y : (j == 2) ? rr.z : rr.w;
            if (c >= lo && c < hi) {
                int slot = atomicAdd(&cnt[c], 1);
                if (slot < CAP) {
                    srcs[(size_t)c * CAP + slot] = (unsigned short)r;
                } else {
                    int oi = atomicAdd(ovf_cnt, 1);
                    ovf[oi] = make_int2(r, c);
                }
            }
        }
    }
    // remainder edges (E % 4, or everything if int4 path disabled)
    for (int e = E4 * 4 + bg * 256 + threadIdx.x; e < E; e += stride) {
        int c = col[e];
        if (c >= lo && c < hi) {
            int r = row[e];
            int slot = atomicAdd(&cnt[c], 1);
            if (slot < CAP) {
                srcs[(size_t)c * CAP + slot] = (unsigned short)r;
            } else {
                int oi = atomicAdd(ovf_cnt, 1);
                ovf[oi] = make_int2(r, c);
            }
        }
    }
}

// ---- K3: per-target gather, 8-wide MLP; bias+PReLU+overflow fused ----------
// One wave per target node; lane = output channel. No output atomics.
__global__ void __launch_bounds__(256) gather_kernel(
    const int* __restrict__ cnt, const unsigned short* __restrict__ srcs,
    const __hip_bfloat16* __restrict__ h,
    const float* __restrict__ b, const float* __restrict__ prelu_a,
    const int* __restrict__ ovf_cnt, const int2* __restrict__ ovf,
    float* __restrict__ out, int n)
{
    int wave = (blockIdx.x * blockDim.x + threadIdx.x) >> 6;
    int lane = threadIdx.x & 63;
    if (wave >= n) return;
    int c = wave;

    int deg = cnt[c];
    int m = deg < CAP ? deg : CAP;
    float dc = rsqrtf((float)deg + 1.0f);

    // lane j holds source j and its edge weight (one coalesced 128B read)
    int   s  = 0;
    float wl = 0.0f;
    if (lane < m) {
        s  = (int)srcs[(size_t)c * CAP + lane];
        wl = rsqrtf((float)cnt[s] + 1.0f) * dc;
    }

    // self-loop term + bias
    float acc = __bfloat162float(h[(size_t)c * D + lane]) * dc * dc + b[lane];

    // 8-wide unrolled edge loop: batch shuffles, then 8 independent loads.
    // Lanes k+j >= m broadcast wl==0, s==0 -> contributes exactly 0.
    int m8 = (m + 7) & ~7;
    for (int k = 0; k < m8; k += 8) {
        int   ss[8];
        float ww[8];
        #pragma unroll
        for (int j = 0; j < 8; ++j) {
            ss[j] = __shfl(s,  k + j);
            ww[j] = __shfl(wl, k + j);
        }
        float vv[8];
        #pragma unroll
        for (int j = 0; j < 8; ++j) {
            vv[j] = __bfloat162float(h[(size_t)ss[j] * D + lane]);
        }
        #pragma unroll
        for (int j = 0; j < 8; ++j) {
            acc += vv[j] * ww[j];
        }
    }

    // overflow fallback (nov == 0 in practice: single scalar load)
    int nov = *ovf_cnt;
    for (int i = 0; i < nov; ++i) {
        int2 rc = ovf[i];
        if (rc.y == c) {
            acc += __bfloat162float(h[(size_t)rc.x * D + lane]) *
                   rsqrtf((float)cnt[rc.x] + 1.0f) * dc;
        }
    }

    float al = prelu_a[0];
    out[(size_t)c * D + lane] = acc >= 0.0f ? acc : al * acc;
}

extern "C" void kernel_launch(void* const* d_in, const int* in_sizes, int n_in,
                              void* d_out, int out_size, void* d_ws, size_t ws_size,
                              hipStream_t stream) {
    const float* x       = (const float*)d_in[0];
    const int*   eidx    = (const int*)d_in[1];   // [2, E] flat
    const float* W       = (const float*)d_in[2];
    const float* b       = (const float*)d_in[3];
    const float* prelu_a = (const float*)d_in[4];

    const int E = in_sizes[1] / 2;
    const int n = in_sizes[0] / D;                // 50000
    const int* row = eidx;
    const int* col = eidx + E;

    float* out = (float*)d_out;

    // int4 path only if both halves are 16B-aligned
    int E4 = 0;
    if ((E % 4) == 0 &&
        ((uintptr_t)row % 16) == 0 && ((uintptr_t)col % 16) == 0) {
        E4 = E / 4;
    }

    // Workspace layout:
    //   cnt      int[n]
    //   ovf_cnt  int[1]
    //   pad      int[1]            (keeps ovf 8B aligned)
    //   ovf      int2[E]           (zero-overshoot from cnt-zeroing lands here: harmless)
    //   h        bf16[n*D]         (6.4 MB)
    //   srcs     ushort[n*CAP]     (6.4 MB)
    int*   cnt     = (int*)d_ws;
    int*   ovf_cnt = cnt + n;
    int2*  ovf     = (int2*)(cnt + n + 2);
    __hip_bfloat16* h = (__hip_bfloat16*)(ovf + E);
    unsigned short* srcs = (unsigned short*)(h + (size_t)n * D);

    // zero cnt[n] + ovf_cnt via int4 stores inside the GEMM kernel
    int nzero4 = (n + 1 + 3) / 4;   // 12501 int4 (overshoot into pad/ovf ok)

    gemm_zero_kernel<<<(n + 3) / 4, 256, 0, stream>>>(
        x, W, h, (int4*)cnt, nzero4, n);

    // 2048 blocks = 256 per XCD group
    fill_kernel<<<2048, 256, 0, stream>>>(
        row, col, (const int4*)row, (const int4*)col,
        cnt, srcs, ovf_cnt, ovf, E, E4, n);

    gather_kernel<<<(n * 64 + 255) / 256, 256, 0, stream>>>(
        cnt, srcs, h, b, prelu_a, ovf_cnt, ovf, out, n);
}